// Round 7
// baseline (211.804 us; speedup 1.0000x reference)
//
#include <hip/hip_runtime.h>
#include <stdint.h>

#define BN 4
#define CD 256
#define ND 4096
#define NK 32            // key-tile size in attention

typedef unsigned short u16;
typedef short bfrag __attribute__((ext_vector_type(8)));  // 8 bf16 = 4 VGPR
typedef float ffrag __attribute__((ext_vector_type(4)));  // MFMA C/D frag

__device__ __forceinline__ float bf2f(u16 u) {
  union { unsigned int i; float f; } v;
  v.i = ((unsigned int)u) << 16;
  return v.f;
}
__device__ __forceinline__ u16 f2bf(float f) {
  union { float f; unsigned int i; } v;
  v.f = f;
  return (u16)((v.i + 0x7FFFu + ((v.i >> 16) & 1u)) >> 16);  // RNE
}
// async global->LDS DMA, 16B per lane; LDS dest = wave-uniform base + lane*16
__device__ __forceinline__ void gload_lds(const u16* g, u16* l) {
  __builtin_amdgcn_global_load_lds(
      (const __attribute__((address_space(1))) void*)g,
      (__attribute__((address_space(3))) void*)l, 16, 0, 0);
}

// ---------- Q/K projection, fused input-transpose + weight-cast ----------
// grid (4, 256, 2): x=n-tile(d), y=m-tile(row), z=0:Q,1:K
// out[m][d] = sum_c in[b][c][m] * W[d][c] + bias[d]   (out row-major [B*N][C])
__global__ __launch_bounds__(256, 2) void k_projQK(
    const float* __restrict__ x, const float* __restrict__ y,
    const float* __restrict__ Wq, const float* __restrict__ Wk,
    const float* __restrict__ bq, const float* __restrict__ bk,
    u16* __restrict__ Qb, u16* __restrict__ Kb) {
  __shared__ alignas(16) u16 As[64][264];  // As[n][c], input^T cast
  __shared__ alignas(16) u16 Bs[64][136];  // Bs[d][c], weights, K in 2 halves
  int n0 = blockIdx.x * 64;  // d offset in [0,256)
  int m0 = blockIdx.y * 64;  // global row in [0,16384)
  int z = blockIdx.z;
  int b = m0 >> 12, nsp = m0 & 4095;
  const float* src = (z ? y : x) + (size_t)b * CD * ND;
  const float* Wsrc = (z ? Wk : Wq) + (size_t)n0 * CD;
  const float* bias = (z ? bk : bq) + n0;
  u16* Cd = (z ? Kb : Qb) + (size_t)m0 * CD + n0;
  int t = threadIdx.x, w = t >> 6, l = t & 63;
  int lane16 = l & 15, quad = l >> 4;

  // A: As[nl][c] = src[c][nsp+nl], all 256 c (transpose+cast in LDS)
#pragma unroll
  for (int it = 0; it < 16; ++it) {
    int idx = it * 256 + t;
    int c = idx >> 4, nj = (idx & 15) * 4;
    float4 v = *(const float4*)(src + (size_t)c * ND + nsp + nj);
    As[nj + 0][c] = f2bf(v.x);
    As[nj + 1][c] = f2bf(v.y);
    As[nj + 2][c] = f2bf(v.z);
    As[nj + 3][c] = f2bf(v.w);
  }

  ffrag acc[4];
#pragma unroll
  for (int tt = 0; tt < 4; ++tt) acc[tt] = ffrag{0.f, 0.f, 0.f, 0.f};
#pragma unroll
  for (int half = 0; half < 2; ++half) {
    if (half) __syncthreads();
    // B: 64 rows x 128 c fp32 -> bf16
#pragma unroll
    for (int it = 0; it < 8; ++it) {
      int idx = it * 256 + t;
      int row = idx >> 5, cj = (idx & 31) * 4;
      float4 v = *(const float4*)(Wsrc + (size_t)row * CD + half * 128 + cj);
      ushort4 o;
      o.x = f2bf(v.x); o.y = f2bf(v.y); o.z = f2bf(v.z); o.w = f2bf(v.w);
      *(ushort4*)&Bs[row][cj] = o;
    }
    __syncthreads();
#pragma unroll
    for (int kc = 0; kc < 4; ++kc) {
      bfrag af = *(const bfrag*)&As[w * 16 + lane16][half * 128 + kc * 32 + quad * 8];
#pragma unroll
      for (int tt = 0; tt < 4; ++tt) {
        bfrag bfr = *(const bfrag*)&Bs[tt * 16 + lane16][kc * 32 + quad * 8];
        acc[tt] = __builtin_amdgcn_mfma_f32_16x16x32_bf16(af, bfr, acc[tt], 0, 0, 0);
      }
    }
  }
#pragma unroll
  for (int tt = 0; tt < 4; ++tt) {
    int colL = tt * 16 + lane16;
    float bcol = bias[colL];
#pragma unroll
    for (int r = 0; r < 4; ++r) {
      int rowL = w * 16 + quad * 4 + r;
      Cd[(size_t)rowL * CD + colL] = f2bf(acc[tt][r] + bcol);
    }
  }
}

// ---------- V projection (transposed output Vt[b][d][n]) ----------
// grid (64, 4, 4): x=n-tile, y=d-tile, z=b
// Vt[b][d][n] = sum_c Wv[d][c] * y[b][c][n] + bv[d]
__global__ __launch_bounds__(256, 2) void k_projV(
    const float* __restrict__ y, const float* __restrict__ Wv,
    const float* __restrict__ bv, u16* __restrict__ Vb) {
  __shared__ alignas(16) u16 As[64][264];  // As[d][c] = Wv cast
  __shared__ alignas(16) u16 Bs[64][136];  // Bs[n][c] = y^T cast, K halves
  int n0s = blockIdx.x * 64;
  int m0 = blockIdx.y * 64;  // d offset
  int b = blockIdx.z;
  const float* Bsrc = y + (size_t)b * CD * ND + n0s;
  u16* Cd = Vb + ((size_t)b * CD + m0) * ND + n0s;
  int t = threadIdx.x, w = t >> 6, l = t & 63;
  int lane16 = l & 15, quad = l >> 4;

  // A = Wv rows m0.., direct cast, full 256 k
#pragma unroll
  for (int it = 0; it < 16; ++it) {
    int idx = it * 256 + t;
    int row = idx >> 6, cj = (idx & 63) * 4;
    float4 v = *(const float4*)(Wv + (size_t)(m0 + row) * CD + cj);
    ushort4 o;
    o.x = f2bf(v.x); o.y = f2bf(v.y); o.z = f2bf(v.z); o.w = f2bf(v.w);
    *(ushort4*)&As[row][cj] = o;
  }

  ffrag acc[4];
#pragma unroll
  for (int tt = 0; tt < 4; ++tt) acc[tt] = ffrag{0.f, 0.f, 0.f, 0.f};
#pragma unroll
  for (int half = 0; half < 2; ++half) {
    if (half) __syncthreads();
    // B = y transposed: Bs[nl][cl] = Bsrc[(half*128+cl)*ND + nl]
#pragma unroll
    for (int it = 0; it < 8; ++it) {
      int idx = it * 256 + t;
      int cl = idx >> 4, nj = (idx & 15) * 4;
      float4 v = *(const float4*)(Bsrc + (size_t)(half * 128 + cl) * ND + nj);
      Bs[nj + 0][cl] = f2bf(v.x);
      Bs[nj + 1][cl] = f2bf(v.y);
      Bs[nj + 2][cl] = f2bf(v.z);
      Bs[nj + 3][cl] = f2bf(v.w);
    }
    __syncthreads();
#pragma unroll
    for (int kc = 0; kc < 4; ++kc) {
      bfrag af = *(const bfrag*)&As[w * 16 + lane16][half * 128 + kc * 32 + quad * 8];
#pragma unroll
      for (int tt = 0; tt < 4; ++tt) {
        bfrag bfr = *(const bfrag*)&Bs[tt * 16 + lane16][kc * 32 + quad * 8];
        acc[tt] = __builtin_amdgcn_mfma_f32_16x16x32_bf16(af, bfr, acc[tt], 0, 0, 0);
      }
    }
  }
  // C[rowL=d][colL=n], bias per-row
#pragma unroll
  for (int tt = 0; tt < 4; ++tt) {
    int colL = tt * 16 + lane16;
#pragma unroll
    for (int r = 0; r < 4; ++r) {
      int rowL = w * 16 + quad * 4 + r;
      Cd[(size_t)rowL * ND + colL] = f2bf(acc[tt][r] + bv[m0 + rowL]);
    }
  }
}

// ---------- flash attention, split-K, async-DMA double-buffered ----------
// Q,K: [B*N][C]; Vt: [B][C][N]. 128 q-rows/block, 4 waves x 2 m-tiles.
// One __syncthreads per K-tile. XOR-swizzled unpadded LDS (global_load_lds).
union SmemU {
  struct {
    u16 Ks[2][NK][256];   // 32,768 B  chunk^=(row&7) swizzle
    u16 Vs[2][CD][NK];    // 32,768 B  chunk^=((d>>1)&3) swizzle
    u16 Ps[8][16][40];    // 10,240 B  wave-private P staging
  } a;                     // 75,776 B
  u16 ot[CD][136];         // 69,632 B  epilogue O^T staging
};

template <int NS>
__global__ __launch_bounds__(256, 2) void k_attn(
    const u16* __restrict__ Q, const u16* __restrict__ K,
    const u16* __restrict__ Vt, u16* __restrict__ O01,
    u16* __restrict__ O23, float* __restrict__ Lpart) {
  constexpr int NIT = ND / NS / NK;
  __shared__ alignas(16) SmemU sm;
  int b = blockIdx.y, q0 = blockIdx.x * 128, z = blockIdx.z;
  int t = threadIdx.x, w = t >> 6, l = t & 63;
  int lane16 = l & 15, quad = l >> 4;
  const float scale = 0.0625f;  // 256^-0.5

  // Q frags: A-layout rows q0 + (w*2+mi)*16 + lane16
  bfrag qf[2][8];
#pragma unroll
  for (int mi = 0; mi < 2; ++mi) {
    const u16* Qrow =
        Q + ((size_t)b * ND + q0 + (w * 2 + mi) * 16 + lane16) * CD;
#pragma unroll
    for (int kc = 0; kc < 8; ++kc)
      qf[mi][kc] = *(const bfrag*)(Qrow + kc * 32 + quad * 8);
  }

  ffrag o[2][16];
#pragma unroll
  for (int mi = 0; mi < 2; ++mi)
#pragma unroll
    for (int i = 0; i < 16; ++i) o[mi][i] = ffrag{0.f, 0.f, 0.f, 0.f};
  float lsum[2][4] = {{0.f, 0.f, 0.f, 0.f}, {0.f, 0.f, 0.f, 0.f}};

  const u16* Kb = K + ((size_t)b * ND + z * (ND / NS)) * CD;
  const u16* Vb = Vt + (size_t)b * CD * ND + z * (ND / NS);

  auto stage = [&](int kt2) {
    int dbuf = kt2 & 1;
    const u16* Kt = Kb + (size_t)kt2 * NK * CD;
    const u16* Vtt = Vb + kt2 * NK;
#pragma unroll
    for (int p = 0; p < 4; ++p) {
      int r = p * 8 + w * 2 + (l >> 5);
      int j = (l & 31) ^ (r & 7);
      gload_lds(Kt + (size_t)r * CD + j * 8, &sm.a.Ks[dbuf][p * 8 + w * 2][0]);
    }
#pragma unroll
    for (int p = 0; p < 4; ++p) {
      int dd = p * 64 + w * 16 + (l >> 2);
      int j = (l & 3) ^ ((dd >> 1) & 3);
      gload_lds(Vtt + (size_t)dd * ND + j * 8, &sm.a.Vs[dbuf][p * 64 + w * 16][0]);
    }
  };

  stage(0);
  for (int kt = 0; kt < NIT; ++kt) {
    int dbuf = kt & 1;
    __syncthreads();  // drains DMA for buf dbuf; recycling of dbuf^1 is safe
    if (kt + 1 < NIT) stage(kt + 1);  // async into other buffer, no wait

    // S = Q K^T  (2 m-tiles x 2 key-tiles)
    ffrag s2[2][2];
#pragma unroll
    for (int mi = 0; mi < 2; ++mi)
#pragma unroll
      for (int tt = 0; tt < 2; ++tt) s2[mi][tt] = ffrag{0.f, 0.f, 0.f, 0.f};
#pragma unroll
    for (int kc = 0; kc < 8; ++kc) {
      bfrag kf0, kf1;
      {
        int r = lane16;
        int cp = (kc * 4 + quad) ^ (r & 7);
        kf0 = *(const bfrag*)&sm.a.Ks[dbuf][r][cp * 8];
        int r1 = 16 + lane16;
        int cp1 = (kc * 4 + quad) ^ (r1 & 7);
        kf1 = *(const bfrag*)&sm.a.Ks[dbuf][r1][cp1 * 8];
      }
#pragma unroll
      for (int mi = 0; mi < 2; ++mi) {
        s2[mi][0] = __builtin_amdgcn_mfma_f32_16x16x32_bf16(qf[mi][kc], kf0,
                                                            s2[mi][0], 0, 0, 0);
        s2[mi][1] = __builtin_amdgcn_mfma_f32_16x16x32_bf16(qf[mi][kc], kf1,
                                                            s2[mi][1], 0, 0, 0);
      }
    }

    // fixed-max softmax: p = exp(s*scale); lane-partial sums; P -> LDS
#pragma unroll
    for (int mi = 0; mi < 2; ++mi)
#pragma unroll
      for (int tt = 0; tt < 2; ++tt)
#pragma unroll
        for (int r = 0; r < 4; ++r) {
          float p = __expf(s2[mi][tt][r] * scale);
          lsum[mi][r] += p;
          sm.a.Ps[w * 2 + mi][quad * 4 + r][tt * 16 + lane16] = f2bf(p);
        }
    // wave-private Ps: in-wave LDS ordering suffices, no barrier
    bfrag pf0 = *(const bfrag*)&sm.a.Ps[w * 2 + 0][lane16][quad * 8];
    bfrag pf1 = *(const bfrag*)&sm.a.Ps[w * 2 + 1][lane16][quad * 8];

    // O += P V  (16 d-tiles, V-frag shared across both m-tiles)
#pragma unroll
    for (int dt = 0; dt < 16; ++dt) {
      int dd = dt * 16 + lane16;
      int cp = quad ^ ((dd >> 1) & 3);
      bfrag vf = *(const bfrag*)&sm.a.Vs[dbuf][dd][cp * 8];
      o[0][dt] = __builtin_amdgcn_mfma_f32_16x16x32_bf16(pf0, vf, o[0][dt], 0, 0, 0);
      o[1][dt] = __builtin_amdgcn_mfma_f32_16x16x32_bf16(pf1, vf, o[1][dt], 0, 0, 0);
    }
  }

  // row-sum reduction: 16-lane butterfly within quad groups, once
#pragma unroll
  for (int mi = 0; mi < 2; ++mi)
#pragma unroll
    for (int r = 0; r < 4; ++r) {
#pragma unroll
      for (int off = 1; off < 16; off <<= 1)
        lsum[mi][r] += __shfl_xor(lsum[mi][r], off, 64);
    }
  if (lane16 == 0) {
#pragma unroll
    for (int mi = 0; mi < 2; ++mi)
#pragma unroll
      for (int r = 0; r < 4; ++r)
        Lpart[((size_t)z * BN + b) * ND + q0 + (w * 2 + mi) * 16 + quad * 4 + r] =
            lsum[mi][r];
  }

  __syncthreads();
  // unnormalized O -> transposed bf16 staging ot[d][q_local]
#pragma unroll
  for (int mi = 0; mi < 2; ++mi)
#pragma unroll
    for (int dt = 0; dt < 16; ++dt)
#pragma unroll
      for (int r = 0; r < 4; ++r)
        sm.ot[dt * 16 + lane16][(w * 2 + mi) * 16 + quad * 4 + r] =
            f2bf(o[mi][dt][r]);
  __syncthreads();
  const size_t SZc = (size_t)BN * ND * CD;
  u16* Op = ((z < 2) ? O01 : O23) + (size_t)(z & 1) * SZc;
#pragma unroll
  for (int it = 0; it < 16; ++it) {
    int c = it * 256 + t;
    int dd = c >> 4, co = (c & 15) * 8;
    size_t g = ((size_t)b * CD + dd) * ND + q0 + co;
    *(uint4*)(Op + g) = *(const uint4*)&sm.ot[dd][co];
  }
}

// ---------- combine partials + residual ----------
template <int NS>
__global__ __launch_bounds__(256) void k_combine(
    const u16* __restrict__ O01, const u16* __restrict__ O23,
    const float* __restrict__ L, const float* __restrict__ x,
    float* __restrict__ out) {
  const size_t SZc = (size_t)BN * ND * CD;
  size_t e = ((size_t)blockIdx.x * 256 + threadIdx.x) * 8;
  int n = (int)(e & (ND - 1));
  int b = (int)(e >> 20);  // C*N = 2^20
  float ls[8] = {0, 0, 0, 0, 0, 0, 0, 0};
  float acc[8] = {0, 0, 0, 0, 0, 0, 0, 0};
#pragma unroll
  for (int z = 0; z < NS; ++z) {
    const float* Lr = L + ((size_t)z * BN + b) * ND + n;
    float4 l0 = *(const float4*)(Lr);
    float4 l1 = *(const float4*)(Lr + 4);
    ls[0] += l0.x; ls[1] += l0.y; ls[2] += l0.z; ls[3] += l0.w;
    ls[4] += l1.x; ls[5] += l1.y; ls[6] += l1.z; ls[7] += l1.w;
    const u16* Oz = ((z < 2) ? O01 : O23) + (size_t)(z & 1) * SZc + e;
    union { uint4 q; u16 s[8]; } u;
    u.q = *(const uint4*)Oz;
#pragma unroll
    for (int j = 0; j < 8; ++j) acc[j] += bf2f(u.s[j]);
  }
  float4 x0 = *(const float4*)(x + e);
  float4 x1 = *(const float4*)(x + e + 4);
  float4 r0, r1;
  r0.x = x0.x + acc[0] / ls[0];
  r0.y = x0.y + acc[1] / ls[1];
  r0.z = x0.z + acc[2] / ls[2];
  r0.w = x0.w + acc[3] / ls[3];
  r1.x = x1.x + acc[4] / ls[4];
  r1.y = x1.y + acc[5] / ls[5];
  r1.z = x1.z + acc[6] / ls[6];
  r1.w = x1.w + acc[7] / ls[7];
  *(float4*)(out + e) = r0;
  *(float4*)(out + e + 4) = r1;
}

extern "C" void kernel_launch(void* const* d_in, const int* in_sizes, int n_in,
                              void* d_out, int out_size, void* d_ws, size_t ws_size,
                              hipStream_t stream) {
  const float* x  = (const float*)d_in[0];
  const float* y  = (const float*)d_in[1];
  const float* Wq = (const float*)d_in[2];
  const float* bq = (const float*)d_in[3];
  const float* Wk = (const float*)d_in[4];
  const float* bk = (const float*)d_in[5];
  const float* Wv = (const float*)d_in[6];
  const float* bv = (const float*)d_in[7];
  float* out = (float*)d_out;
  u16* ws = (u16*)d_ws;
  const size_t SZ = (size_t)BN * ND * CD;  // 4,194,304 elems per tensor
  u16* Qb = ws;
  u16* Kb = Qb + SZ;
  u16* Vb = Kb + SZ;
  u16* Ob = Vb + SZ;  // NS partials, contiguous
  // NS=4 needs: 7*SZ bf16 + 4*BN*ND fp32 = 58.7 MB + 256 KB
  const size_t need4 = 7 * SZ * sizeof(u16) + (size_t)4 * BN * ND * sizeof(float);
  const bool big = ws_size >= need4;  // constant across calls (graph-safe)
  const int cgrid = (int)(SZ / (256 * 8));  // 2048 blocks (out = SZ floats)

  k_projQK<<<dim3(4, 256, 2), 256, 0, stream>>>(x, y, Wq, Wk, bq, bk, Qb, Kb);
  k_projV<<<dim3(64, 4, 4), 256, 0, stream>>>(y, Wv, bv, Vb);
  if (big) {
    float* Lp = (float*)(Ob + 4 * SZ);
    k_attn<4><<<dim3(ND / 128, BN, 4), 256, 0, stream>>>(Qb, Kb, Vb, Ob,
                                                         Ob + 2 * SZ, Lp);
    k_combine<4><<<dim3(cgrid), 256, 0, stream>>>(Ob, Ob + 2 * SZ, Lp, x, out);
  } else {
    float* Lp = (float*)(Ob + 2 * SZ);
    k_attn<2><<<dim3(ND / 128, BN, 2), 256, 0, stream>>>(Qb, Kb, Vb, Ob, Ob, Lp);
    k_combine<2><<<dim3(cgrid), 256, 0, stream>>>(Ob, Ob, Lp, x, out);
  }
}